// Round 20
// baseline (47.300 us; speedup 1.0000x reference)
//
#include <hip/hip_runtime.h>
#include <cstdint>
#include <cstddef>

#define N_NODES 4096
#define IN_DIM 256
#define HID 64
#define HEADS 8
#define OUT_DIM 64
#define ALPHA 0.2f
#define MAXDEG 64
#define TILE 8

typedef __attribute__((ext_vector_type(8))) short bf16x8;
typedef __attribute__((ext_vector_type(4))) float f32x4;

__device__ __forceinline__ unsigned short f2bf(float f) {
    unsigned u = __float_as_uint(f);
    u += 0x7fffu + ((u >> 16) & 1u);   // RNE
    return (unsigned short)(u >> 16);
}
__device__ __forceinline__ float bf2f(unsigned short u) {
    return __uint_as_float(((unsigned)u) << 16);
}

// ============ K1: {gemm1 MFMA (bid%9==0)} || {csr 1 row/block} || {WoT bf16 (bid>=4608)} =====
// XCD-aware head/tile derivation: h = q>>6, n0 = (q&63)*64 puts the 8 blocks sharing one
// x-tile on the SAME XCD, so 7/8 x-tile reads hit local L2. (R19 form — measured best.)
__global__ __launch_bounds__(256) void k1_gemm_csr(const float* __restrict__ x,
                                                   const float* __restrict__ W,
                                                   const float* __restrict__ a1,
                                                   const float* __restrict__ a2,
                                                   unsigned short* __restrict__ Whb,
                                                   float* __restrict__ f1,
                                                   float* __restrict__ f2,
                                                   const float* __restrict__ adj,
                                                   int* __restrict__ degs,
                                                   int* __restrict__ cols,
                                                   const float* __restrict__ Wo,
                                                   unsigned short* __restrict__ WoT) {
    __shared__ __attribute__((aligned(16))) unsigned short axs[64][72];    // x chunk [row][k]
    __shared__ __attribute__((aligned(16))) unsigned short bws[64][72];    // W^T chunk [o][k]
    int bid = blockIdx.x;
    int t = threadIdx.x;
    int w = t >> 6, l = t & 63;
    if (bid >= 4608) {
        // ---------------- Wo -> WoT bf16 [o][k] (32 blocks, 16 k-rows each) ----------------
        int k0 = (bid - 4608) * 16;
        #pragma unroll
        for (int i = 0; i < 4; ++i) {
            int e = t + i * 256;
            int kk = k0 + (e >> 6);
            int o = e & 63;
            WoT[(size_t)o * 512 + kk] = f2bf(Wo[(size_t)kk * OUT_DIM + o]);
        }
        return;
    }
    if (bid % 9 == 0) {
        // ---------------- GEMM1 (MFMA) ----------------
        int g = bid / 9;
        int h = g >> 6;              // XCD-aware: co-x-tile blocks share XCD
        int n0 = (g & 63) * 64;
        int m0 = (w >> 1) * 32;      // row quadrant
        int np = (w & 1) * 32;       // col quadrant
        f32x4 zf = {0.f, 0.f, 0.f, 0.f};
        f32x4 acc[2][2] = {{zf, zf}, {zf, zf}};
        const float4* x4 = (const float4*)x;
        const float4* w4 = (const float4*)(W + (size_t)h * IN_DIM * HID);
        for (int kc = 0; kc < IN_DIM; kc += 64) {
            __syncthreads();
            #pragma unroll
            for (int i = 0; i < 4; ++i) {       // x chunk: 64 rows x 64 k
                int e = t + i * 256;
                int r = e >> 4, c4 = e & 15;
                float4 v = x4[(size_t)(n0 + r) * (IN_DIM / 4) + (kc >> 2) + c4];
                ushort4 u;
                u.x = f2bf(v.x); u.y = f2bf(v.y); u.z = f2bf(v.z); u.w = f2bf(v.w);
                *(ushort4*)&axs[r][c4 * 4] = u;
            }
            #pragma unroll
            for (int i = 0; i < 4; ++i) {       // W^T chunk: rows kc..kc+63 -> [o][kk]
                int e = t + i * 256;
                int kk = e >> 4, c4 = e & 15;
                float4 v = w4[(size_t)(kc + kk) * (HID / 4) + c4];
                bws[4 * c4 + 0][kk] = f2bf(v.x);
                bws[4 * c4 + 1][kk] = f2bf(v.y);
                bws[4 * c4 + 2][kk] = f2bf(v.z);
                bws[4 * c4 + 3][kk] = f2bf(v.w);
            }
            __syncthreads();
            #pragma unroll
            for (int k0 = 0; k0 < 64; k0 += 32) {
                bf16x8 af[2], bfr[2];
                #pragma unroll
                for (int m = 0; m < 2; ++m)
                    af[m] = *(const bf16x8*)&axs[m0 + m * 16 + (l & 15)][k0 + (l >> 4) * 8];
                #pragma unroll
                for (int n = 0; n < 2; ++n)
                    bfr[n] = *(const bf16x8*)&bws[np + n * 16 + (l & 15)][k0 + (l >> 4) * 8];
                #pragma unroll
                for (int m = 0; m < 2; ++m)
                    #pragma unroll
                    for (int n = 0; n < 2; ++n)
                        acc[m][n] = __builtin_amdgcn_mfma_f32_16x16x32_bf16(af[m], bfr[n], acc[m][n], 0, 0, 0);
            }
        }
        __syncthreads();   // done with LDS; reuse axs as reduction buffer
        float a1c[2], a2c[2];
        #pragma unroll
        for (int n = 0; n < 2; ++n) {
            a1c[n] = a1[h * HID + np + n * 16 + (l & 15)];
            a2c[n] = a2[h * HID + np + n * 16 + (l & 15)];
        }
        float* fred = (float*)&axs[0][0];   // [2(f)][2(wn)][64(row)]
        int wn = w & 1;
        #pragma unroll
        for (int m = 0; m < 2; ++m) {
            #pragma unroll
            for (int r = 0; r < 4; ++r) {
                int row = m0 + m * 16 + (l >> 4) * 4 + r;
                #pragma unroll
                for (int n = 0; n < 2; ++n)
                    Whb[((size_t)(n0 + row) * HEADS + h) * HID + np + n * 16 + (l & 15)] =
                        f2bf(acc[m][n][r]);
                float s1 = acc[m][0][r] * a1c[0] + acc[m][1][r] * a1c[1];
                float s2 = acc[m][0][r] * a2c[0] + acc[m][1][r] * a2c[1];
                #pragma unroll
                for (int off = 8; off; off >>= 1) {
                    s1 += __shfl_xor(s1, off);
                    s2 += __shfl_xor(s2, off);
                }
                if ((l & 15) == 0) {
                    fred[0 * 128 + wn * 64 + row] = s1;
                    fred[1 * 128 + wn * 64 + row] = s2;
                }
            }
        }
        __syncthreads();
        if (t < 64) {
            f1[(size_t)(n0 + t) * HEADS + h] = fred[t] + fred[64 + t];
            f2[(size_t)(n0 + t) * HEADS + h] = fred[128 + t] + fred[192 + t];
        }
    } else {
        // ---------------- CSR build: one block per adj row ----------------
        int g = bid / 9, r9 = bid % 9;
        int row = g * 8 + r9 - 1;               // 0..4095
        int* wcols = (int*)&axs[0][0];          // [4][MAXDEG] overlay on LDS
        int* wcnt  = (int*)&bws[0][0];          // [4]
        const float4* arow = (const float4*)(adj + (size_t)row * N_NODES);
        float4 v0 = arow[w * 256 + 0 * 64 + l];
        float4 v1 = arow[w * 256 + 1 * 64 + l];
        float4 v2 = arow[w * 256 + 2 * 64 + l];
        float4 v3 = arow[w * 256 + 3 * 64 + l];
        int base = 0;
        float4 vv[4] = {v0, v1, v2, v3};
        #pragma unroll
        for (int i = 0; i < 4; ++i) {
            float comp[4] = {vv[i].x, vv[i].y, vv[i].z, vv[i].w};
            #pragma unroll
            for (int q = 0; q < 4; ++q) {
                bool pred = comp[q] > 0.f;
                unsigned long long mask = __ballot(pred);
                if (pred) {
                    int pos = base + __popcll(mask & ((1ull << l) - 1ull));
                    if (pos < MAXDEG) wcols[w * MAXDEG + pos] = (w * 256 + i * 64 + l) * 4 + q;
                }
                base += __popcll(mask);
            }
        }
        if (l == 0) wcnt[w] = base < MAXDEG ? base : MAXDEG;
        __syncthreads();
        int c0 = wcnt[0], c1 = wcnt[1], c2 = wcnt[2], c3 = wcnt[3];
        int off = (w > 0 ? c0 : 0) + (w > 1 ? c1 : 0) + (w > 2 ? c2 : 0);
        int mycnt = wcnt[w];
        if (l < mycnt) {
            int gpos = off + l;
            if (gpos < MAXDEG) cols[row * MAXDEG + gpos] = wcols[w * MAXDEG + l];
        }
        if (t == 0) {
            int tot = c0 + c1 + c2 + c3;
            degs[row] = tot < MAXDEG ? tot : MAXDEG;
        }
    }
}

// ================= K23: fused attn1 + gemm2 per 8-node tile (512 blocks) =============
// B1: stage degs/cols + ALL f2 scores into pf via 256 parallel indep loads (no serial chain).
// B2: softmax per (node,head) thread, entirely from LDS.
// B3: gather 32 threads/node, 8-DEEP unroll (16 loads in flight, mirrors K4's pattern).
// C:  gemm2 MFMA from htile + staged WoT, fused f-epilogue (Wh2 fp32).
__global__ __launch_bounds__(256) void attn1_gemm2(const unsigned short* __restrict__ Whb,
                                                   const float* __restrict__ f1,
                                                   const float* __restrict__ f2,
                                                   const int* __restrict__ degs,
                                                   const int* __restrict__ cols,
                                                   const unsigned short* __restrict__ WoT,
                                                   const float* __restrict__ a1,
                                                   const float* __restrict__ a2,
                                                   float* __restrict__ Wh2,
                                                   float* __restrict__ f1o,
                                                   float* __restrict__ f2o) {
    __shared__ int   cols_s[TILE][MAXDEG];                                   // 2KB
    __shared__ int   deg_s[TILE];
    __shared__ float f1s[TILE * HEADS];
    __shared__ float pf[TILE][65][8];                                        // 16.6KB (j-padded)
    __shared__ __attribute__((aligned(16))) unsigned short htile[16][520];   // 16.6KB
    __shared__ __attribute__((aligned(16))) unsigned short bws[64][136];     // 17.4KB
    __shared__ float fred[2][4][TILE];

    int n0 = blockIdx.x * TILE;
    int t = threadIdx.x;
    int w = t >> 6, l = t & 63;

    // ---- B1a: stage degs + cols + f1; zero htile pad rows 8..15 ----
    if (t < TILE) deg_s[t] = degs[n0 + t];
    if (t < TILE * HEADS) f1s[t] = f1[(size_t)n0 * HEADS + t];
    {
        int nl = t >> 5, ix = t & 31;
        cols_s[nl][ix]      = cols[(size_t)(n0 + nl) * MAXDEG + ix];
        cols_s[nl][ix + 32] = cols[(size_t)(n0 + nl) * MAXDEG + ix + 32];
    }
    {
        uint4 z = {0u, 0u, 0u, 0u};
        #pragma unroll
        for (int i = 0; i < 2; ++i) {
            int e = t + i * 256;               // 0..511
            int r = 8 + (e >> 6), c8 = e & 63;
            *(uint4*)&htile[r][c8 * 8] = z;
        }
    }
    __syncthreads();

    // ---- B1b: stage f2 scores -> pf[nl][j][h], 16 indep loads/thread ----
    #pragma unroll
    for (int it = 0; it < 16; ++it) {
        int slot = t + it * 256;               // 0..4095
        int nl = slot >> 9;
        int rem = slot & 511;
        int j = rem >> 3, h = rem & 7;
        if (j < deg_s[nl]) {
            int c = cols_s[nl][j];
            pf[nl][j][h] = f2[(size_t)c * HEADS + h];
        }
    }
    __syncthreads();

    // ---- B2: softmax, thread = (node, head), all from LDS ----
    if (t < TILE * HEADS) {
        int nl = t >> 3, h = t & 7;
        int deg = deg_s[nl];
        float f1v = f1s[t];
        float m = -1e30f;
        for (int j = 0; j < deg; ++j) {
            float v = f1v + pf[nl][j][h];
            v = v > 0.f ? v : ALPHA * v;
            pf[nl][j][h] = v;
            m = fmaxf(m, v);
        }
        float s = 0.f;
        for (int j = 0; j < deg; ++j) {
            float p = expf(pf[nl][j][h] - m);
            pf[nl][j][h] = p;
            s += p;
        }
        float inv = 1.f / s;
        for (int j = 0; j < deg; ++j) pf[nl][j][h] *= inv;
    }
    __syncthreads();

    // ---- B3: gather -> htile rows 0..7. nl = t>>5, s = t&31; 8-deep unroll ----
    {
        int nl = t >> 5, s = t & 31;
        int deg = deg_s[nl];
        int hA = s >> 3, hB = 4 + (s >> 3);
        float accA[8] = {}, accB[8] = {};
        const uint4* whp = (const uint4*)Whb;  // 64 uint4 per node row (512 bf16)
        int j = 0;
        for (; j + 8 <= deg; j += 8) {
            uint4 ua[8], ub[8];
            float pa[8], pb[8];
            #pragma unroll
            for (int q = 0; q < 8; ++q) {
                int c = cols_s[nl][j + q];
                ua[q] = whp[(size_t)c * 64 + s];
                ub[q] = whp[(size_t)c * 64 + 32 + s];
            }
            #pragma unroll
            for (int q = 0; q < 8; ++q) {
                pa[q] = pf[nl][j + q][hA];
                pb[q] = pf[nl][j + q][hB];
            }
            #pragma unroll
            for (int q = 0; q < 8; ++q) {
                const unsigned short* wa = (const unsigned short*)&ua[q];
                const unsigned short* wb = (const unsigned short*)&ub[q];
                #pragma unroll
                for (int r = 0; r < 8; ++r) {
                    accA[r] += pa[q] * bf2f(wa[r]);
                    accB[r] += pb[q] * bf2f(wb[r]);
                }
            }
        }
        for (; j + 2 <= deg; j += 2) {
            int c0 = cols_s[nl][j], c1 = cols_s[nl][j + 1];
            uint4 u0a = whp[(size_t)c0 * 64 + s];
            uint4 u0b = whp[(size_t)c0 * 64 + 32 + s];
            uint4 u1a = whp[(size_t)c1 * 64 + s];
            uint4 u1b = whp[(size_t)c1 * 64 + 32 + s];
            float p0a = pf[nl][j][hA],     p0b = pf[nl][j][hB];
            float p1a = pf[nl][j + 1][hA], p1b = pf[nl][j + 1][hB];
            const unsigned short* w0a = (const unsigned short*)&u0a;
            const unsigned short* w0b = (const unsigned short*)&u0b;
            const unsigned short* w1a = (const unsigned short*)&u1a;
            const unsigned short* w1b = (const unsigned short*)&u1b;
            #pragma unroll
            for (int q = 0; q < 8; ++q) {
                accA[q] += p0a * bf2f(w0a[q]) + p1a * bf2f(w1a[q]);
                accB[q] += p0b * bf2f(w0b[q]) + p1b * bf2f(w1b[q]);
            }
        }
        if (j < deg) {
            int c0 = cols_s[nl][j];
            uint4 u0a = whp[(size_t)c0 * 64 + s];
            uint4 u0b = whp[(size_t)c0 * 64 + 32 + s];
            float p0a = pf[nl][j][hA], p0b = pf[nl][j][hB];
            const unsigned short* w0a = (const unsigned short*)&u0a;
            const unsigned short* w0b = (const unsigned short*)&u0b;
            #pragma unroll
            for (int q = 0; q < 8; ++q) {
                accA[q] += p0a * bf2f(w0a[q]);
                accB[q] += p0b * bf2f(w0b[q]);
            }
        }
        unsigned short ovA[8], ovB[8];
        #pragma unroll
        for (int q = 0; q < 8; ++q) { ovA[q] = f2bf(accA[q]); ovB[q] = f2bf(accB[q]); }
        *(uint4*)&htile[nl][s * 8]       = *(const uint4*)ovA;
        *(uint4*)&htile[nl][256 + s * 8] = *(const uint4*)ovB;
    }

    // ---- C: gemm2 MFMA from htile; wave w -> cols [w*16, w*16+16) ----
    f32x4 gacc = {0.f, 0.f, 0.f, 0.f};
    int nbase = w * 16;
    for (int kc = 0; kc < HEADS * HID; kc += 128) {
        __syncthreads();   // htile ready (1st iter) / prev MFMA done with bws
        #pragma unroll
        for (int i = 0; i < 4; ++i) {      // stage WoT chunk: 64 o-rows x 128 k, 16B copies
            int e = t + i * 256;
            int o = e >> 4, c8 = e & 15;
            *(uint4*)&bws[o][c8 * 8] = *(const uint4*)&WoT[(size_t)o * 512 + kc + c8 * 8];
        }
        __syncthreads();
        #pragma unroll
        for (int k0 = 0; k0 < 128; k0 += 32) {
            bf16x8 af = *(const bf16x8*)&htile[l & 15][kc + k0 + (l >> 4) * 8];
            bf16x8 bfr = *(const bf16x8*)&bws[nbase + (l & 15)][k0 + (l >> 4) * 8];
            gacc = __builtin_amdgcn_mfma_f32_16x16x32_bf16(af, bfr, gacc, 0, 0, 0);
        }
    }
    // ---- epilogue: Wh2 + fused f1_2/f2_2 (valid rows 0..7 only) ----
    float a1c = a1[nbase + (l & 15)];
    float a2c = a2[nbase + (l & 15)];
    #pragma unroll
    for (int r = 0; r < 4; ++r) {
        int row = (l >> 4) * 4 + r;        // 0..15
        float s1 = gacc[r] * a1c;
        float s2 = gacc[r] * a2c;
        #pragma unroll
        for (int off = 8; off; off >>= 1) {
            s1 += __shfl_xor(s1, off);
            s2 += __shfl_xor(s2, off);
        }
        if (row < TILE) {
            Wh2[(size_t)(n0 + row) * OUT_DIM + nbase + (l & 15)] = gacc[r];
            if ((l & 15) == 0) {
                fred[0][w][row] = s1;
                fred[1][w][row] = s2;
            }
        }
    }
    __syncthreads();
    if (t < TILE) {
        f1o[n0 + t] = fred[0][0][t] + fred[0][1][t] + fred[0][2][t] + fred[0][3][t];
        f2o[n0 + t] = fred[1][0][t] + fred[1][1][t] + fred[1][2][t] + fred[1][3][t];
    }
}

// ================= K4: attention layer 2 (+ELU), 1 wave per node, 8-deep gather =============
__global__ __launch_bounds__(256) void attn2(const float* __restrict__ Wh,
                                             const float* __restrict__ f1,
                                             const float* __restrict__ f2,
                                             const int* __restrict__ degs,
                                             const int* __restrict__ cols,
                                             float* __restrict__ out) {
    int wave = threadIdx.x >> 6;
    int lane = threadIdx.x & 63;
    int n = blockIdx.x * 4 + wave;
    if (n >= N_NODES) return;
    int deg = degs[n];
    int col = 0;
    float e = -1e30f;
    if (lane < deg) {
        col = cols[n * MAXDEG + lane];
        float v = f1[n] + f2[col];
        e = v > 0.f ? v : ALPHA * v;
    }
    float m = e;
    #pragma unroll
    for (int off = 32; off; off >>= 1) m = fmaxf(m, __shfl_xor(m, off));
    float p = (lane < deg) ? expf(e - m) : 0.f;
    float s = p;
    #pragma unroll
    for (int off = 32; off; off >>= 1) s += __shfl_xor(s, off);
    float inv = 1.f / s;
    float acc = 0.f;
    int j = 0;
    for (; j + 8 <= deg; j += 8) {
        int cj[8]; float pj[8]; float v[8];
        #pragma unroll
        for (int q = 0; q < 8; ++q) cj[q] = __shfl(col, j + q);
        #pragma unroll
        for (int q = 0; q < 8; ++q) pj[q] = __shfl(p, j + q);
        #pragma unroll
        for (int q = 0; q < 8; ++q) v[q] = Wh[(size_t)cj[q] * OUT_DIM + lane];
        #pragma unroll
        for (int q = 0; q < 8; ++q) acc += pj[q] * v[q];
    }
    for (; j < deg; ++j) {
        int cj = __shfl(col, j);
        float pj = __shfl(p, j);
        acc += pj * Wh[(size_t)cj * OUT_DIM + lane];
    }
    acc *= inv;
    acc = acc > 0.f ? acc : expf(acc) - 1.f;   // ELU
    out[(size_t)n * OUT_DIM + lane] = acc;
}

extern "C" void kernel_launch(void* const* d_in, const int* in_sizes, int n_in,
                              void* d_out, int out_size, void* d_ws, size_t ws_size,
                              hipStream_t stream) {
    const float* x    = (const float*)d_in[0];
    const float* adj  = (const float*)d_in[1];
    const float* W_h  = (const float*)d_in[2];
    const float* a1_h = (const float*)d_in[3];
    const float* a2_h = (const float*)d_in[4];
    const float* W_o  = (const float*)d_in[5];
    const float* a1_o = (const float*)d_in[6];
    const float* a2_o = (const float*)d_in[7];
    float* out = (float*)d_out;

    float* wsf  = (float*)d_ws;
    float* Wh2  = wsf;                                  // [n][64] fp32
    float* f1_1 = Wh2 + (size_t)N_NODES * OUT_DIM;      // [n][8]
    float* f2_1 = f1_1 + (size_t)N_NODES * HEADS;
    float* f1_2 = f2_1 + (size_t)N_NODES * HEADS;       // [n]
    float* f2_2 = f1_2 + N_NODES;
    int*   degs = (int*)(f2_2 + N_NODES);
    int*   csr  = degs + N_NODES;                       // [n][64]
    unsigned short* Whb = (unsigned short*)(csr + (size_t)N_NODES * MAXDEG);   // bf16 [n][h][o]
    unsigned short* WoT = Whb + (size_t)N_NODES * HEADS * HID;                 // bf16 [64][512]

    // K1: gemm1-MFMA (512) || csr (4096, 1/row) || WoT conversion (32)
    k1_gemm_csr<<<4640, 256, 0, stream>>>(x, W_h, a1_h, a2_h, Whb, f1_1, f2_1,
                                          adj, degs, csr, W_o, WoT);

    // K23: fused attn1 + gemm2 per 8-node tile (512 blocks)
    attn1_gemm2<<<N_NODES / TILE, 256, 0, stream>>>(Whb, f1_1, f2_1, degs, csr,
                                                    WoT, a1_o, a2_o, Wh2, f1_2, f2_2);

    // K4: attention layer 2 + ELU -> d_out [n][64]
    attn2<<<N_NODES / 4, 256, 0, stream>>>(Wh2, f1_2, f2_2, degs, csr, out);
}

// Round 21
// 46.088 us; speedup vs baseline: 1.0263x; 1.0263x over previous
//
#include <hip/hip_runtime.h>
#include <cstdint>
#include <cstddef>

#define N_NODES 4096
#define IN_DIM 256
#define HID 64
#define HEADS 8
#define OUT_DIM 64
#define ALPHA 0.2f
#define MAXDEG 64
#define TILE 8

typedef __attribute__((ext_vector_type(8))) short bf16x8;
typedef __attribute__((ext_vector_type(4))) float f32x4;

__device__ __forceinline__ unsigned short f2bf(float f) {
    unsigned u = __float_as_uint(f);
    u += 0x7fffu + ((u >> 16) & 1u);   // RNE
    return (unsigned short)(u >> 16);
}
__device__ __forceinline__ float bf2f(unsigned short u) {
    return __uint_as_float(((unsigned)u) << 16);
}

// ============ K1: {gemm1 MFMA (bid%9==0)} || {csr 1 row/block} || {WoT bf16 (bid>=4608)} =====
// XCD-aware head/tile derivation: h = q>>6, n0 = (q&63)*64 puts the 8 blocks sharing one
// x-tile on the SAME XCD, so 7/8 x-tile reads hit local L2. (R19 form — measured best.)
__global__ __launch_bounds__(256) void k1_gemm_csr(const float* __restrict__ x,
                                                   const float* __restrict__ W,
                                                   const float* __restrict__ a1,
                                                   const float* __restrict__ a2,
                                                   unsigned short* __restrict__ Whb,
                                                   float* __restrict__ f1,
                                                   float* __restrict__ f2,
                                                   const float* __restrict__ adj,
                                                   int* __restrict__ degs,
                                                   int* __restrict__ cols,
                                                   const float* __restrict__ Wo,
                                                   unsigned short* __restrict__ WoT) {
    __shared__ __attribute__((aligned(16))) unsigned short axs[64][72];    // x chunk [row][k]
    __shared__ __attribute__((aligned(16))) unsigned short bws[64][72];    // W^T chunk [o][k]
    int bid = blockIdx.x;
    int t = threadIdx.x;
    int w = t >> 6, l = t & 63;
    if (bid >= 4608) {
        // ---------------- Wo -> WoT bf16 [o][k] (32 blocks, 16 k-rows each) ----------------
        int k0 = (bid - 4608) * 16;
        #pragma unroll
        for (int i = 0; i < 4; ++i) {
            int e = t + i * 256;
            int kk = k0 + (e >> 6);
            int o = e & 63;
            WoT[(size_t)o * 512 + kk] = f2bf(Wo[(size_t)kk * OUT_DIM + o]);
        }
        return;
    }
    if (bid % 9 == 0) {
        // ---------------- GEMM1 (MFMA) ----------------
        int g = bid / 9;
        int h = g >> 6;              // XCD-aware: co-x-tile blocks share XCD
        int n0 = (g & 63) * 64;
        int m0 = (w >> 1) * 32;      // row quadrant
        int np = (w & 1) * 32;       // col quadrant
        f32x4 zf = {0.f, 0.f, 0.f, 0.f};
        f32x4 acc[2][2] = {{zf, zf}, {zf, zf}};
        const float4* x4 = (const float4*)x;
        const float4* w4 = (const float4*)(W + (size_t)h * IN_DIM * HID);
        for (int kc = 0; kc < IN_DIM; kc += 64) {
            __syncthreads();
            #pragma unroll
            for (int i = 0; i < 4; ++i) {       // x chunk: 64 rows x 64 k
                int e = t + i * 256;
                int r = e >> 4, c4 = e & 15;
                float4 v = x4[(size_t)(n0 + r) * (IN_DIM / 4) + (kc >> 2) + c4];
                ushort4 u;
                u.x = f2bf(v.x); u.y = f2bf(v.y); u.z = f2bf(v.z); u.w = f2bf(v.w);
                *(ushort4*)&axs[r][c4 * 4] = u;
            }
            #pragma unroll
            for (int i = 0; i < 4; ++i) {       // W^T chunk: rows kc..kc+63 -> [o][kk]
                int e = t + i * 256;
                int kk = e >> 4, c4 = e & 15;
                float4 v = w4[(size_t)(kc + kk) * (HID / 4) + c4];
                bws[4 * c4 + 0][kk] = f2bf(v.x);
                bws[4 * c4 + 1][kk] = f2bf(v.y);
                bws[4 * c4 + 2][kk] = f2bf(v.z);
                bws[4 * c4 + 3][kk] = f2bf(v.w);
            }
            __syncthreads();
            #pragma unroll
            for (int k0 = 0; k0 < 64; k0 += 32) {
                bf16x8 af[2], bfr[2];
                #pragma unroll
                for (int m = 0; m < 2; ++m)
                    af[m] = *(const bf16x8*)&axs[m0 + m * 16 + (l & 15)][k0 + (l >> 4) * 8];
                #pragma unroll
                for (int n = 0; n < 2; ++n)
                    bfr[n] = *(const bf16x8*)&bws[np + n * 16 + (l & 15)][k0 + (l >> 4) * 8];
                #pragma unroll
                for (int m = 0; m < 2; ++m)
                    #pragma unroll
                    for (int n = 0; n < 2; ++n)
                        acc[m][n] = __builtin_amdgcn_mfma_f32_16x16x32_bf16(af[m], bfr[n], acc[m][n], 0, 0, 0);
            }
        }
        __syncthreads();   // done with LDS; reuse axs as reduction buffer
        float a1c[2], a2c[2];
        #pragma unroll
        for (int n = 0; n < 2; ++n) {
            a1c[n] = a1[h * HID + np + n * 16 + (l & 15)];
            a2c[n] = a2[h * HID + np + n * 16 + (l & 15)];
        }
        float* fred = (float*)&axs[0][0];   // [2(f)][2(wn)][64(row)]
        int wn = w & 1;
        #pragma unroll
        for (int m = 0; m < 2; ++m) {
            #pragma unroll
            for (int r = 0; r < 4; ++r) {
                int row = m0 + m * 16 + (l >> 4) * 4 + r;
                #pragma unroll
                for (int n = 0; n < 2; ++n)
                    Whb[((size_t)(n0 + row) * HEADS + h) * HID + np + n * 16 + (l & 15)] =
                        f2bf(acc[m][n][r]);
                float s1 = acc[m][0][r] * a1c[0] + acc[m][1][r] * a1c[1];
                float s2 = acc[m][0][r] * a2c[0] + acc[m][1][r] * a2c[1];
                #pragma unroll
                for (int off = 8; off; off >>= 1) {
                    s1 += __shfl_xor(s1, off);
                    s2 += __shfl_xor(s2, off);
                }
                if ((l & 15) == 0) {
                    fred[0 * 128 + wn * 64 + row] = s1;
                    fred[1 * 128 + wn * 64 + row] = s2;
                }
            }
        }
        __syncthreads();
        if (t < 64) {
            f1[(size_t)(n0 + t) * HEADS + h] = fred[t] + fred[64 + t];
            f2[(size_t)(n0 + t) * HEADS + h] = fred[128 + t] + fred[192 + t];
        }
    } else {
        // ---------------- CSR build: one block per adj row ----------------
        int g = bid / 9, r9 = bid % 9;
        int row = g * 8 + r9 - 1;               // 0..4095
        int* wcols = (int*)&axs[0][0];          // [4][MAXDEG] overlay on LDS
        int* wcnt  = (int*)&bws[0][0];          // [4]
        const float4* arow = (const float4*)(adj + (size_t)row * N_NODES);
        float4 v0 = arow[w * 256 + 0 * 64 + l];
        float4 v1 = arow[w * 256 + 1 * 64 + l];
        float4 v2 = arow[w * 256 + 2 * 64 + l];
        float4 v3 = arow[w * 256 + 3 * 64 + l];
        int base = 0;
        float4 vv[4] = {v0, v1, v2, v3};
        #pragma unroll
        for (int i = 0; i < 4; ++i) {
            float comp[4] = {vv[i].x, vv[i].y, vv[i].z, vv[i].w};
            #pragma unroll
            for (int q = 0; q < 4; ++q) {
                bool pred = comp[q] > 0.f;
                unsigned long long mask = __ballot(pred);
                if (pred) {
                    int pos = base + __popcll(mask & ((1ull << l) - 1ull));
                    if (pos < MAXDEG) wcols[w * MAXDEG + pos] = (w * 256 + i * 64 + l) * 4 + q;
                }
                base += __popcll(mask);
            }
        }
        if (l == 0) wcnt[w] = base < MAXDEG ? base : MAXDEG;
        __syncthreads();
        int c0 = wcnt[0], c1 = wcnt[1], c2 = wcnt[2], c3 = wcnt[3];
        int off = (w > 0 ? c0 : 0) + (w > 1 ? c1 : 0) + (w > 2 ? c2 : 0);
        int mycnt = wcnt[w];
        if (l < mycnt) {
            int gpos = off + l;
            if (gpos < MAXDEG) cols[row * MAXDEG + gpos] = wcols[w * MAXDEG + l];
        }
        if (t == 0) {
            int tot = c0 + c1 + c2 + c3;
            degs[row] = tot < MAXDEG ? tot : MAXDEG;
        }
    }
}

// ================= K23: fused attn1 + gemm2 per 8-node tile (512 blocks, 2/CU) =============
// R19 form + chunk-0 WoT pre-staging: bws is dead until phase C, so its first chunk is
// staged BEFORE the long B3 gather (overlaps the load latency); C-loop stages chunk k+1
// after the MFMA on chunk k.
__global__ __launch_bounds__(256) void attn1_gemm2(const unsigned short* __restrict__ Whb,
                                                   const float* __restrict__ f1,
                                                   const float* __restrict__ f2,
                                                   const int* __restrict__ degs,
                                                   const int* __restrict__ cols,
                                                   const unsigned short* __restrict__ WoT,
                                                   const float* __restrict__ a1,
                                                   const float* __restrict__ a2,
                                                   float* __restrict__ Wh2,
                                                   float* __restrict__ f1o,
                                                   float* __restrict__ f2o) {
    __shared__ int   cols_s[TILE][MAXDEG];                                   // 2KB
    __shared__ int   deg_s[TILE];
    __shared__ float p_s[TILE][HEADS][MAXDEG];                               // 16KB
    __shared__ __attribute__((aligned(16))) unsigned short htile[16][520];   // 16.6KB
    __shared__ __attribute__((aligned(16))) unsigned short bws[64][136];     // 17.4KB
    __shared__ float fred[2][4][TILE];

    int n0 = blockIdx.x * TILE;
    int t = threadIdx.x;
    int w = t >> 6, l = t & 63;

    // ---- B1: stage degs + cols; zero htile pad rows 8..15; pre-stage WoT chunk 0 ----
    if (t < TILE) deg_s[t] = degs[n0 + t];
    {
        int nl = t >> 5, ix = t & 31;
        cols_s[nl][ix]      = cols[(size_t)(n0 + nl) * MAXDEG + ix];
        cols_s[nl][ix + 32] = cols[(size_t)(n0 + nl) * MAXDEG + ix + 32];
    }
    {
        uint4 z = {0u, 0u, 0u, 0u};
        #pragma unroll
        for (int i = 0; i < 2; ++i) {
            int e = t + i * 256;               // 0..511
            int r = 8 + (e >> 6), c8 = e & 63;
            *(uint4*)&htile[r][c8 * 8] = z;
        }
    }
    #pragma unroll
    for (int i = 0; i < 4; ++i) {              // WoT chunk 0: 64 o-rows x 128 k, 16B copies
        int e = t + i * 256;
        int o = e >> 4, c8 = e & 15;
        *(uint4*)&bws[o][c8 * 8] = *(const uint4*)&WoT[(size_t)o * 512 + c8 * 8];
    }
    __syncthreads();

    // ---- B2: softmax, thread = (node, head), 64 threads ----
    if (t < TILE * HEADS) {
        int nl = t >> 3, h = t & 7;
        int deg = deg_s[nl];
        float f1v = f1[(size_t)(n0 + nl) * HEADS + h];
        float m = -1e30f;
        for (int j = 0; j < deg; ++j) {
            int c = cols_s[nl][j];
            float v = f1v + f2[(size_t)c * HEADS + h];
            v = v > 0.f ? v : ALPHA * v;
            p_s[nl][h][j] = v;
            m = fmaxf(m, v);
        }
        float s = 0.f;
        for (int j = 0; j < deg; ++j) {
            float p = expf(p_s[nl][h][j] - m);
            p_s[nl][h][j] = p;
            s += p;
        }
        float inv = 1.f / s;
        for (int j = 0; j < deg; ++j) p_s[nl][h][j] *= inv;
    }
    __syncthreads();

    // ---- B3: gather -> htile rows 0..7. nl = t>>5, s = t&31; 2-deep unroll ----
    {
        int nl = t >> 5, s = t & 31;
        int deg = deg_s[nl];
        int hA = s >> 3, hB = 4 + (s >> 3);    // heads for dim slices [s*8) and [256+s*8)
        float accA[8] = {}, accB[8] = {};
        const uint4* whp = (const uint4*)Whb;  // 64 uint4 per node row (512 bf16)
        int j = 0;
        for (; j + 2 <= deg; j += 2) {
            int c0 = cols_s[nl][j], c1 = cols_s[nl][j + 1];
            uint4 u0a = whp[(size_t)c0 * 64 + s];
            uint4 u0b = whp[(size_t)c0 * 64 + 32 + s];
            uint4 u1a = whp[(size_t)c1 * 64 + s];
            uint4 u1b = whp[(size_t)c1 * 64 + 32 + s];
            float p0a = p_s[nl][hA][j],     p0b = p_s[nl][hB][j];
            float p1a = p_s[nl][hA][j + 1], p1b = p_s[nl][hB][j + 1];
            const unsigned short* w0a = (const unsigned short*)&u0a;
            const unsigned short* w0b = (const unsigned short*)&u0b;
            const unsigned short* w1a = (const unsigned short*)&u1a;
            const unsigned short* w1b = (const unsigned short*)&u1b;
            #pragma unroll
            for (int q = 0; q < 8; ++q) {
                accA[q] += p0a * bf2f(w0a[q]) + p1a * bf2f(w1a[q]);
                accB[q] += p0b * bf2f(w0b[q]) + p1b * bf2f(w1b[q]);
            }
        }
        if (j < deg) {
            int c0 = cols_s[nl][j];
            uint4 u0a = whp[(size_t)c0 * 64 + s];
            uint4 u0b = whp[(size_t)c0 * 64 + 32 + s];
            float p0a = p_s[nl][hA][j], p0b = p_s[nl][hB][j];
            const unsigned short* w0a = (const unsigned short*)&u0a;
            const unsigned short* w0b = (const unsigned short*)&u0b;
            #pragma unroll
            for (int q = 0; q < 8; ++q) {
                accA[q] += p0a * bf2f(w0a[q]);
                accB[q] += p0b * bf2f(w0b[q]);
            }
        }
        unsigned short ovA[8], ovB[8];
        #pragma unroll
        for (int q = 0; q < 8; ++q) { ovA[q] = f2bf(accA[q]); ovB[q] = f2bf(accB[q]); }
        *(uint4*)&htile[nl][s * 8]       = *(const uint4*)ovA;
        *(uint4*)&htile[nl][256 + s * 8] = *(const uint4*)ovB;
    }

    // ---- C: gemm2 MFMA from htile; wave w -> cols [w*16, w*16+16) ----
    // chunk kc is already in bws at loop top (chunk 0 pre-staged in B1).
    f32x4 gacc = {0.f, 0.f, 0.f, 0.f};
    int nbase = w * 16;
    for (int kc = 0; kc < HEADS * HID; kc += 128) {
        __syncthreads();   // htile ready (1st iter) / staged bws chunk visible
        #pragma unroll
        for (int k0 = 0; k0 < 128; k0 += 32) {
            bf16x8 af = *(const bf16x8*)&htile[l & 15][kc + k0 + (l >> 4) * 8];
            bf16x8 bfr = *(const bf16x8*)&bws[nbase + (l & 15)][k0 + (l >> 4) * 8];
            gacc = __builtin_amdgcn_mfma_f32_16x16x32_bf16(af, bfr, gacc, 0, 0, 0);
        }
        if (kc + 128 < HEADS * HID) {
            __syncthreads();   // all waves done reading bws chunk kc
            #pragma unroll
            for (int i = 0; i < 4; ++i) {      // stage WoT chunk kc+128
                int e = t + i * 256;
                int o = e >> 4, c8 = e & 15;
                *(uint4*)&bws[o][c8 * 8] =
                    *(const uint4*)&WoT[(size_t)o * 512 + kc + 128 + c8 * 8];
            }
        }
    }
    // ---- epilogue: Wh2 + fused f1_2/f2_2 (valid rows 0..7 only) ----
    float a1c = a1[nbase + (l & 15)];
    float a2c = a2[nbase + (l & 15)];
    #pragma unroll
    for (int r = 0; r < 4; ++r) {
        int row = (l >> 4) * 4 + r;        // 0..15
        float s1 = gacc[r] * a1c;
        float s2 = gacc[r] * a2c;
        #pragma unroll
        for (int off = 8; off; off >>= 1) {
            s1 += __shfl_xor(s1, off);
            s2 += __shfl_xor(s2, off);
        }
        if (row < TILE) {
            Wh2[(size_t)(n0 + row) * OUT_DIM + nbase + (l & 15)] = gacc[r];
            if ((l & 15) == 0) {
                fred[0][w][row] = s1;
                fred[1][w][row] = s2;
            }
        }
    }
    __syncthreads();
    if (t < TILE) {
        f1o[n0 + t] = fred[0][0][t] + fred[0][1][t] + fred[0][2][t] + fred[0][3][t];
        f2o[n0 + t] = fred[1][0][t] + fred[1][1][t] + fred[1][2][t] + fred[1][3][t];
    }
}

// ================= K4: attention layer 2 (+ELU), 1 wave per node, 8-deep gather =============
__global__ __launch_bounds__(256) void attn2(const float* __restrict__ Wh,
                                             const float* __restrict__ f1,
                                             const float* __restrict__ f2,
                                             const int* __restrict__ degs,
                                             const int* __restrict__ cols,
                                             float* __restrict__ out) {
    int wave = threadIdx.x >> 6;
    int lane = threadIdx.x & 63;
    int n = blockIdx.x * 4 + wave;
    if (n >= N_NODES) return;
    int deg = degs[n];
    int col = 0;
    float e = -1e30f;
    if (lane < deg) {
        col = cols[n * MAXDEG + lane];
        float v = f1[n] + f2[col];
        e = v > 0.f ? v : ALPHA * v;
    }
    float m = e;
    #pragma unroll
    for (int off = 32; off; off >>= 1) m = fmaxf(m, __shfl_xor(m, off));
    float p = (lane < deg) ? expf(e - m) : 0.f;
    float s = p;
    #pragma unroll
    for (int off = 32; off; off >>= 1) s += __shfl_xor(s, off);
    float inv = 1.f / s;
    float acc = 0.f;
    int j = 0;
    for (; j + 8 <= deg; j += 8) {
        int cj[8]; float pj[8]; float v[8];
        #pragma unroll
        for (int q = 0; q < 8; ++q) cj[q] = __shfl(col, j + q);
        #pragma unroll
        for (int q = 0; q < 8; ++q) pj[q] = __shfl(p, j + q);
        #pragma unroll
        for (int q = 0; q < 8; ++q) v[q] = Wh[(size_t)cj[q] * OUT_DIM + lane];
        #pragma unroll
        for (int q = 0; q < 8; ++q) acc += pj[q] * v[q];
    }
    for (; j < deg; ++j) {
        int cj = __shfl(col, j);
        float pj = __shfl(p, j);
        acc += pj * Wh[(size_t)cj * OUT_DIM + lane];
    }
    acc *= inv;
    acc = acc > 0.f ? acc : expf(acc) - 1.f;   // ELU
    out[(size_t)n * OUT_DIM + lane] = acc;
}

extern "C" void kernel_launch(void* const* d_in, const int* in_sizes, int n_in,
                              void* d_out, int out_size, void* d_ws, size_t ws_size,
                              hipStream_t stream) {
    const float* x    = (const float*)d_in[0];
    const float* adj  = (const float*)d_in[1];
    const float* W_h  = (const float*)d_in[2];
    const float* a1_h = (const float*)d_in[3];
    const float* a2_h = (const float*)d_in[4];
    const float* W_o  = (const float*)d_in[5];
    const float* a1_o = (const float*)d_in[6];
    const float* a2_o = (const float*)d_in[7];
    float* out = (float*)d_out;

    float* wsf  = (float*)d_ws;
    float* Wh2  = wsf;                                  // [n][64] fp32
    float* f1_1 = Wh2 + (size_t)N_NODES * OUT_DIM;      // [n][8]
    float* f2_1 = f1_1 + (size_t)N_NODES * HEADS;
    float* f1_2 = f2_1 + (size_t)N_NODES * HEADS;       // [n]
    float* f2_2 = f1_2 + N_NODES;
    int*   degs = (int*)(f2_2 + N_NODES);
    int*   csr  = degs + N_NODES;                       // [n][64]
    unsigned short* Whb = (unsigned short*)(csr + (size_t)N_NODES * MAXDEG);   // bf16 [n][h][o]
    unsigned short* WoT = Whb + (size_t)N_NODES * HEADS * HID;                 // bf16 [64][512]

    // K1: gemm1-MFMA (512) || csr (4096, 1/row) || WoT conversion (32)
    k1_gemm_csr<<<4640, 256, 0, stream>>>(x, W_h, a1_h, a2_h, Whb, f1_1, f2_1,
                                          adj, degs, csr, W_o, WoT);

    // K23: fused attn1 + gemm2 per 8-node tile (512 blocks, 2 blocks/CU)
    attn1_gemm2<<<N_NODES / TILE, 256, 0, stream>>>(Whb, f1_1, f2_1, degs, csr,
                                                    WoT, a1_o, a2_o, Wh2, f1_2, f2_2);

    // K4: attention layer 2 + ELU -> d_out [n][64]
    attn2<<<N_NODES / 4, 256, 0, stream>>>(Wh2, f1_2, f2_2, degs, csr, out);
}